// Round 16
// baseline (79.869 us; speedup 1.0000x reference)
//
#include <hip/hip_runtime.h>
#include <hip/hip_fp16.h>

#define H 64
#define NA 65536
#define NB 131072
#define NM 16384
#define NC 2048
#define E_AC 65536
#define E_BC 131072
#define E_MC 16384
#define NE_TOT (E_AC + E_BC + E_MC)

#define CAPA 160
#define CAPB 224
#define CAPM 96
#define SLOTB (NC * CAPA)
#define SLOTM (SLOTB + NC * CAPB)
#define SLOT_TOT (SLOTM + NC * CAPM)

typedef __attribute__((ext_vector_type(8))) short bf16x8;
typedef __attribute__((ext_vector_type(4))) float f32x4;

__device__ __forceinline__ float sigmoidf_(float x) { return 1.0f / (1.0f + __expf(-x)); }
__device__ __forceinline__ float softplusf_(float x) {
    return fmaxf(x, 0.0f) + __logf(1.0f + __expf(-fabsf(x)));
}
__device__ __forceinline__ short bf16_of(float f) {
    union { float f; unsigned u; } v; v.f = f;
    unsigned r = (v.u + 0x7fff + ((v.u >> 16) & 1)) >> 16;  // RNE
    return (short)r;
}
__device__ __forceinline__ float bf16_to_f(short h) {
    union { unsigned u; float f; } v; v.u = ((unsigned)(unsigned short)h) << 16;
    return v.f;
}

// Column-permuted pack position: actual col c (0..63), part = 0(f)/1(s).
__device__ __forceinline__ size_t pack_pos(int k, int col, int S) {
    int part = col >> 6, c = col & 63;
    int t = (c & 3) + part * 4;
    int lo = c >> 2;
    int sm = k >> 5, q = (k >> 3) & 3, e = k & 7;
    return (size_t)(((t * S + sm) * 64) + q * 16 + lo) * 8 + e;
}

// ================= K0: prep0 (413 blocks; cnt pre-zeroed by memsetAsync) =============
// [0,104): edge append  [104,232): xb8 pack  [232,280): atom pack S=3
// [280,312): motif pack S=2  [312,408): cell pack 3x S=2
// 408: biasA  409: biasM  410: biasC  [411,413): WcB
__global__ __launch_bounds__(256) void prep0_kernel(
    const float* __restrict__ xb,
    const float* __restrict__ Wa, const float* __restrict__ ba,
    const float* __restrict__ Wb, const float* __restrict__ bb_,
    const float* __restrict__ Wm, const float* __restrict__ bm,
    const float* __restrict__ Wf, const float* __restrict__ bf,
    const float* __restrict__ Ws, const float* __restrict__ bs,
    const int* __restrict__ ea, const int* __restrict__ eb, const int* __restrict__ em,
    short* __restrict__ xb8,
    short* __restrict__ wpA, short* __restrict__ wpM, short* __restrict__ wpC,
    float* __restrict__ biasA, float* __restrict__ biasM, float* __restrict__ biasC,
    __half2* __restrict__ WcB, int* __restrict__ cnt, int* __restrict__ slots)
{
    int b = blockIdx.x, tid = threadIdx.x;
    if (b < 104) {                            // edge append (cnt already zeroed)
        int t0 = b * 256 + tid;
        #pragma unroll
        for (int u2 = 0; u2 < 8; ++u2) {
            int i = t0 + u2 * 26624;
            int r, d, s;
            if (i < E_AC)             { r = 0; s = ea[i];                 d = ea[E_AC + i]; }
            else if (i < E_AC + E_BC) { int k = i - E_AC; r = 1; s = eb[k]; d = eb[E_BC + k]; }
            else                      { int k = i - E_AC - E_BC; r = 2; s = NA + em[k]; d = em[E_MC + k]; }
            int pos = atomicAdd(&cnt[r * NC + d], 1);
            int base, cap;
            if (r == 0)      { base = d * CAPA;         cap = CAPA; }
            else if (r == 1) { base = SLOTB + d * CAPB; cap = CAPB; }
            else             { base = SLOTM + d * CAPM; cap = CAPM; }
            if (pos < cap) slots[base + pos] = s;
        }
    } else if (b < 232) {                     // xb8: bond features -> bf16x8 rows
        int bb = b - 104;
        for (int r = bb * 1024 + tid; r < bb * 1024 + 1024; r += 256) {
            const float* p = xb + (size_t)r * 7;
            bf16x8 h;
            #pragma unroll
            for (int k = 0; k < 7; ++k) h[k] = bf16_of(p[k]);
            h[7] = 0;
            *(bf16x8*)(xb8 + (size_t)r * 8) = h;
        }
    } else if (b < 280) {                     // atom composite pack: 96x128, S=3
        int idx = (b - 232) * 256 + tid;
        int k = idx >> 7, col = idx & 127, c = col & 63;
        const float* WB = ((col < 64) ? Wf : Ws) + (size_t)6 * 2 * H * H + (size_t)H * H;
        float v = 0.0f;
        if (k < 92) {
            const float* a = Wa + (size_t)k * H;
            for (int j = 0; j < H; ++j) v = fmaf(a[j], WB[j * H + c], v);
        }
        wpA[pack_pos(k, col, 3)] = bf16_of(v);
    } else if (b < 312) {                     // motif composite pack: 64x128, S=2
        int idx = (b - 280) * 256 + tid;
        int k = idx >> 7, col = idx & 127, c = col & 63;
        const float* WB = ((col < 64) ? Wf : Ws) + (size_t)8 * 2 * H * H + (size_t)H * H;
        float v = 0.0f;
        if (k < 35) {
            const float* a = Wm + (size_t)k * H;
            for (int j = 0; j < H; ++j) v = fmaf(a[j], WB[j * H + c], v);
        }
        wpM[pack_pos(k, col, 2)] = bf16_of(v);
    } else if (b < 408) {                     // cell top-half relayout: 3 x 64x128, S=2
        int cu = b - 312;
        int rel = cu >> 5;
        int idx = (cu & 31) * 256 + tid;
        int k = idx >> 7, col = idx & 127, c = col & 63;
        float v = ((col < 64) ? Wf : Ws)[(size_t)(6 + rel) * 2 * H * H + (size_t)k * H + c];
        wpC[(size_t)rel * 8192 + pack_pos(k, col, 2)] = bf16_of(v);
    } else if (b == 408) {
        if (tid < 128) {
            int col = tid, c = col & 63;
            const float* WB = ((col < 64) ? Wf : Ws) + (size_t)6 * 2 * H * H + (size_t)H * H;
            float v = 0.0f;
            for (int j = 0; j < H; ++j) v = fmaf(ba[j], WB[j * H + c], v);
            biasA[col] = v;
        }
    } else if (b == 409) {
        if (tid < 128) {
            int col = tid, c = col & 63;
            const float* WB = ((col < 64) ? Wf : Ws) + (size_t)8 * 2 * H * H + (size_t)H * H;
            float v = 0.0f;
            for (int j = 0; j < H; ++j) v = fmaf(bm[j], WB[j * H + c], v);
            biasM[col] = v;
        }
    } else if (b == 410) {
        for (int i = tid; i < 384; i += 256) {
            int rel = i >> 7, col = i & 127, c = col & 63;
            biasC[rel * 128 + col] = ((col < 64) ? bf : bs)[(6 + rel) * H + c];
        }
    } else {                                  // bond composite weights + bias row
        int idx = (b - 411) * 256 + tid;
        if (idx < 8 * 64) {
            int k = idx >> 6, col = idx & 63;
            const float* WfB = Wf + (size_t)7 * 2 * H * H + (size_t)H * H;
            const float* WsB = Ws + (size_t)7 * 2 * H * H + (size_t)H * H;
            const float* row = (k < 7) ? (Wb + (size_t)k * H) : bb_;
            float f = 0.0f, s = 0.0f;
            for (int j = 0; j < H; ++j) {
                float rv = row[j];
                f = fmaf(rv, WfB[j * H + col], f);
                s = fmaf(rv, WsB[j * H + col], s);
            }
            WcB[k * 64 + col] = __floats2half2_rn(f, s);
        }
    }
}

// ---------------- G build tile: one wave = 16 rows x 128 cols, coalesced stores -------
template<int K, int S, bool VEC>
__device__ __forceinline__ void gmfma_body(
    int blk, const float* __restrict__ x, const short* __restrict__ wp,
    const float* __restrict__ bias, __half2* __restrict__ g)
{
    int l = threadIdx.x & 63;
    int wv = threadIdx.x >> 6;
    int r0 = (blk * 4 + wv) * 16;
    int lrow = l & 15, q = l >> 4;

    float bF[4], bS[4];
    #pragma unroll
    for (int t = 0; t < 4; ++t) {
        bF[t] = bias[lrow * 4 + t];           // col c = lrow*4 + t
        bS[t] = bias[64 + lrow * 4 + t];
    }

    f32x4 acc[8];
    #pragma unroll
    for (int t = 0; t < 8; ++t) acc[t] = (f32x4){0.f, 0.f, 0.f, 0.f};

    const float* xr = x + (size_t)(r0 + lrow) * K;
    #pragma unroll
    for (int s = 0; s < S; ++s) {
        int kb = s * 32 + q * 8;
        bf16x8 afrag;
        if (VEC && kb + 8 <= K) {
            float4 v0 = *(const float4*)(xr + kb);
            float4 v1 = *(const float4*)(xr + kb + 4);
            afrag[0] = bf16_of(v0.x); afrag[1] = bf16_of(v0.y);
            afrag[2] = bf16_of(v0.z); afrag[3] = bf16_of(v0.w);
            afrag[4] = bf16_of(v1.x); afrag[5] = bf16_of(v1.y);
            afrag[6] = bf16_of(v1.z); afrag[7] = bf16_of(v1.w);
        } else {
            #pragma unroll
            for (int e = 0; e < 8; ++e) {
                float xv = 0.0f;
                if (kb + e < K) xv = xr[kb + e];
                afrag[e] = bf16_of(xv);
            }
        }
        #pragma unroll
        for (int t = 0; t < 8; ++t) {
            bf16x8 bt = *(const bf16x8*)(wp + (size_t)((t * S + s) * 64 + l) * 8);
            acc[t] = __builtin_amdgcn_mfma_f32_16x16x32_bf16(afrag, bt, acc[t], 0, 0, 0);
        }
    }

    #pragma unroll
    for (int r = 0; r < 4; ++r) {             // one dwordx4 per row
        __half2 h[4];
        #pragma unroll
        for (int t = 0; t < 4; ++t)
            h[t] = __floats2half2_rn(acc[t][r] + bF[t], acc[t + 4][r] + bS[t]);
        *(float4*)(g + (size_t)(r0 + q * 4 + r) * H + lrow * 4) = *(float4*)h;
    }
}

// ================= K1: work (1376 blocks, pure MFMA G/C builds) =================
// [0,96): cell C  [96,1120): atom G  [1120,1376): motif G
__global__ __launch_bounds__(256) void work_kernel(
    const float* __restrict__ xa, const float* __restrict__ xm, const float* __restrict__ xc,
    const short* __restrict__ wpA, const float* __restrict__ biasA,
    const short* __restrict__ wpM, const float* __restrict__ biasM,
    const short* __restrict__ wpC, const float* __restrict__ biasC,
    __half2* __restrict__ gAll, __half2* __restrict__ Ccomb)
{
    int b = blockIdx.x;
    if (b < 96) {
        int rel = b >> 5, blk = b & 31;
        gmfma_body<64, 2, true>(blk, xc, wpC + (size_t)rel * 8192, biasC + rel * 128,
                                Ccomb + (size_t)rel * NC * H);
    } else if (b < 1120) {
        gmfma_body<92, 3, true>(b - 96, xa, wpA, biasA, gAll);
    } else {
        gmfma_body<35, 2, false>(b - 1120, xm, wpM, biasM, gAll + (size_t)NA * H);
    }
}

// ================= K2: per-cell accumulate + head (2048 blocks x 512) =================
// 16 lanes per edge: lane=(eg=l>>4, cg=l&15); one float4 load = 4 cols of edge eg
// -> one instruction gathers 4 complete edges. shfl_xor(16,32) folds edge-subgroups.
__global__ __launch_bounds__(512) void cellacc_kernel(
    const __half2* __restrict__ gAll, const short* __restrict__ xb8,
    const __half2* __restrict__ WcB,
    const int* __restrict__ slots, const int* __restrict__ cnt,
    const __half2* __restrict__ Ccomb, const float* __restrict__ xc,
    const float* __restrict__ Wp, const float* __restrict__ bp,
    const float* __restrict__ Wo, const float* __restrict__ bo,
    float* __restrict__ out)
{
    __shared__ int   sL[CAPA + CAPB + CAPM];
    __shared__ float red[8][H];
    __shared__ float vL[H];
    int d = blockIdx.x;
    int tid = threadIdx.x, lane = tid & 63, wv = tid >> 6;   // 8 waves
    int eg = lane >> 4, cg = lane & 15;        // edge subgroup / col group (cols cg*4+j)

    int nA = min(cnt[d], CAPA);
    int nB = min(cnt[NC + d], CAPB);
    int nM = min(cnt[2 * NC + d], CAPM);
    for (int i = tid; i < nA; i += 512) sL[i] = slots[d * CAPA + i];
    for (int i = tid; i < nB; i += 512) sL[nA + i] = slots[SLOTB + d * CAPB + i];
    for (int i = tid; i < nM; i += 512) sL[nA + nB + i] = slots[SLOTM + d * CAPM + i];

    // per-lane C values for its 4 cols, all 3 relations
    float2 ccA[4], ccB[4], ccM[4];
    {
        float4 tA = *(const float4*)(Ccomb + (size_t)d * H + cg * 4);
        float4 tB = *(const float4*)(Ccomb + (size_t)(NC + d) * H + cg * 4);
        float4 tM = *(const float4*)(Ccomb + (size_t)(2 * NC + d) * H + cg * 4);
        #pragma unroll
        for (int j = 0; j < 4; ++j) {
            ccA[j] = __half22float2(((__half2*)&tA)[j]);
            ccB[j] = __half22float2(((__half2*)&tB)[j]);
            ccM[j] = __half22float2(((__half2*)&tM)[j]);
        }
    }
    float4 wch[8];                             // bond composite weights, 4 cols x 8 k
    #pragma unroll
    for (int k = 0; k < 8; ++k) wch[k] = *(const float4*)(WcB + k * 64 + cg * 4);
    __syncthreads();

    int ntot = nA + nB + nM, nAB = nA + nB;
    float acc[4] = {0.f, 0.f, 0.f, 0.f};
    int cs = (ntot + 7) >> 3;                  // contiguous chunk per wave
    int p0 = wv * cs, p1 = min(p0 + cs, ntot);

    // ---- sub-loop 1: atom gather (4 edges per float4-load round) ----
    {
        int a1 = min(p1, nA);
        for (int p = p0; p < a1; p += 4) {
            int pc = p + eg;
            float m = (pc < a1) ? 1.0f : 0.0f;
            int row = sL[min(pc, a1 - 1)];
            float4 gv = *(const float4*)(gAll + (size_t)row * H + cg * 4);
            #pragma unroll
            for (int j = 0; j < 4; ++j) {
                float2 a = __half22float2(((__half2*)&gv)[j]);
                acc[j] += m * (sigmoidf_(ccA[j].x + a.x) * softplusf_(ccA[j].y + a.y));
            }
        }
    }
    // ---- sub-loop 2: bond on-the-fly (each 16-lane group owns one edge) ----
    {
        int b0 = max(p0, nA), b1 = min(p1, nAB);
        for (int p = b0; p < b1; p += 4) {
            int pc = p + eg;
            float m = (pc < b1) ? 1.0f : 0.0f;
            int row = sL[min(pc, b1 - 1)];
            bf16x8 xr = *(const bf16x8*)(xb8 + (size_t)row * 8);
            float gf[4], gs[4];
            #pragma unroll
            for (int j = 0; j < 4; ++j) {
                float2 wb = __half22float2(((const __half2*)&wch[7])[j]);
                gf[j] = wb.x; gs[j] = wb.y;
            }
            #pragma unroll
            for (int k = 0; k < 7; ++k) {
                float xv = bf16_to_f(xr[k]);
                #pragma unroll
                for (int j = 0; j < 4; ++j) {
                    float2 w = __half22float2(((const __half2*)&wch[k])[j]);
                    gf[j] = fmaf(xv, w.x, gf[j]);
                    gs[j] = fmaf(xv, w.y, gs[j]);
                }
            }
            #pragma unroll
            for (int j = 0; j < 4; ++j)
                acc[j] += m * (sigmoidf_(ccB[j].x + gf[j]) * softplusf_(ccB[j].y + gs[j]));
        }
    }
    // ---- sub-loop 3: motif gather ----
    {
        int m0 = max(p0, nAB);
        for (int p = m0; p < p1; p += 4) {
            int pc = p + eg;
            float m = (pc < p1) ? 1.0f : 0.0f;
            int row = sL[min(pc, p1 - 1)];
            float4 gv = *(const float4*)(gAll + (size_t)row * H + cg * 4);
            #pragma unroll
            for (int j = 0; j < 4; ++j) {
                float2 a = __half22float2(((__half2*)&gv)[j]);
                acc[j] += m * (sigmoidf_(ccM[j].x + a.x) * softplusf_(ccM[j].y + a.y));
            }
        }
    }

    // fold the 4 edge-subgroups: lanes l, l^16, l^32 hold same cols
    #pragma unroll
    for (int j = 0; j < 4; ++j) {
        acc[j] += __shfl_xor(acc[j], 16, 64);
        acc[j] += __shfl_xor(acc[j], 32, 64);
    }
    if (eg == 0) {
        #pragma unroll
        for (int j = 0; j < 4; ++j) red[wv][cg * 4 + j] = acc[j];
    }
    __syncthreads();

    if (wv == 0) {
        float a = 3.0f * xc[(size_t)d * H + lane];
        #pragma unroll
        for (int w = 0; w < 8; ++w) a += red[w][lane];
        vL[lane] = fmaxf(a, 0.0f);
        __builtin_amdgcn_s_waitcnt(0);   // wave-local LDS drain
        float aj = bp[lane];
        #pragma unroll
        for (int k = 0; k < H; ++k) aj = fmaf(vL[k], Wp[k * H + lane], aj);
        float contrib = softplusf_(aj) * Wo[lane];
        #pragma unroll
        for (int o = 32; o > 0; o >>= 1) contrib += __shfl_down(contrib, o, 64);
        if (lane == 0) out[d] = contrib + bo[0];
    }
}

extern "C" void kernel_launch(void* const* d_in, const int* in_sizes, int n_in,
                              void* d_out, int out_size, void* d_ws, size_t ws_size,
                              hipStream_t stream)
{
    const float* xa = (const float*)d_in[0];
    const float* xb = (const float*)d_in[1];
    const float* xm = (const float*)d_in[2];
    const float* xc = (const float*)d_in[3];
    const float* Wa = (const float*)d_in[4];
    const float* ba = (const float*)d_in[5];
    const float* Wb = (const float*)d_in[6];
    const float* bb_ = (const float*)d_in[7];
    const float* Wm = (const float*)d_in[8];
    const float* bm = (const float*)d_in[9];
    const float* Wf = (const float*)d_in[10];
    const float* bf = (const float*)d_in[11];
    const float* Ws = (const float*)d_in[12];
    const float* bs = (const float*)d_in[13];
    const float* Wp = (const float*)d_in[14];
    const float* bp = (const float*)d_in[15];
    const float* Wo = (const float*)d_in[16];
    const float* bo = (const float*)d_in[17];
    const int* ea = (const int*)d_in[24];
    const int* eb = (const int*)d_in[25];
    const int* em = (const int*)d_in[26];

    // ---- workspace layout (256B-aligned), ~30 MB ----
    char* base = (char*)d_ws;
    size_t o = 0;
    auto alloc = [&](size_t bytes) { char* r = base + o; o = (o + bytes + 255) & ~(size_t)255; return r; };
    int*     cnt   = (int*)    alloc(3 * NC * sizeof(int));
    int*     slots = (int*)    alloc(SLOT_TOT * sizeof(int));
    short*   xb8   = (short*)  alloc((size_t)NB * 8 * sizeof(short));   // 2 MB
    short*   wpA   = (short*)  alloc(8 * 3 * 64 * 8 * sizeof(short));
    short*   wpM   = (short*)  alloc(8 * 2 * 64 * 8 * sizeof(short));
    short*   wpC   = (short*)  alloc(3 * 8192 * sizeof(short));
    float*   biasA = (float*)  alloc(128 * sizeof(float));
    float*   biasM = (float*)  alloc(128 * sizeof(float));
    float*   biasC = (float*)  alloc(384 * sizeof(float));
    __half2* WcB   = (__half2*)alloc(8 * 64 * sizeof(__half2));
    __half2* Ccomb = (__half2*)alloc((size_t)3 * NC * H * sizeof(__half2));
    __half2* gAll  = (__half2*)alloc((size_t)(NA + NM) * H * sizeof(__half2));  // 21 MB
    float*   out   = (float*)d_out;

    hipMemsetAsync(cnt, 0, 3 * NC * sizeof(int), stream);
    prep0_kernel<<<413, 256, 0, stream>>>(xb, Wa, ba, Wb, bb_, Wm, bm, Wf, bf, Ws, bs,
                                          ea, eb, em,
                                          xb8, wpA, wpM, wpC, biasA, biasM, biasC, WcB,
                                          cnt, slots);
    work_kernel<<<1376, 256, 0, stream>>>(xa, xm, xc,
                                          wpA, biasA, wpM, biasM, wpC, biasC,
                                          gAll, Ccomb);
    cellacc_kernel<<<NC, 512, 0, stream>>>(gAll, xb8, WcB, slots, cnt, Ccomb,
                                           xc, Wp, bp, Wo, bo, out);
}

// Round 17
// 71.391 us; speedup vs baseline: 1.1188x; 1.1188x over previous
//
#include <hip/hip_runtime.h>
#include <hip/hip_fp16.h>

#define H 64
#define NA 65536
#define NB 131072
#define NM 16384
#define NC 2048
#define E_AC 65536
#define E_BC 131072
#define E_MC 16384
#define NE_TOT (E_AC + E_BC + E_MC)

#define CAPA 160
#define CAPB 224
#define CAPM 96
#define SLOTB (NC * CAPA)
#define SLOTM (SLOTB + NC * CAPB)
#define SLOT_TOT (SLOTM + NC * CAPM)

typedef __attribute__((ext_vector_type(8))) short bf16x8;
typedef __attribute__((ext_vector_type(4))) float f32x4;

__device__ __forceinline__ float sigmoidf_(float x) { return 1.0f / (1.0f + __expf(-x)); }
__device__ __forceinline__ float softplusf_(float x) {
    return fmaxf(x, 0.0f) + __logf(1.0f + __expf(-fabsf(x)));
}
__device__ __forceinline__ short bf16_of(float f) {
    union { float f; unsigned u; } v; v.f = f;
    unsigned r = (v.u + 0x7fff + ((v.u >> 16) & 1)) >> 16;  // RNE
    return (short)r;
}

// Column-permuted pack position: actual col c (0..63), part = 0(f)/1(s).
// tile t = (c&3) + part*4 ; within-tile col lo = c>>2.
__device__ __forceinline__ size_t pack_pos(int k, int col, int S) {
    int part = col >> 6, c = col & 63;
    int t = (c & 3) + part * 4;
    int lo = c >> 2;
    int sm = k >> 5, q = (k >> 3) & 3, e = k & 7;
    return (size_t)(((t * S + sm) * 64) + q * 16 + lo) * 8 + e;
}

// ================= K0: prep0 — zero cnt + weight packs (196 blocks) =================
// [0,48): atom pack S=3   [48,80): motif pack S=2   [80,176): cell pack 3x S=2
// [176,192): bond pack S=1   192: biasA  193: biasM  194: biasB  195: biasC
__global__ __launch_bounds__(256) void prep0_kernel(
    const float* __restrict__ Wa, const float* __restrict__ ba,
    const float* __restrict__ Wb, const float* __restrict__ bb_,
    const float* __restrict__ Wm, const float* __restrict__ bm,
    const float* __restrict__ Wf, const float* __restrict__ bf,
    const float* __restrict__ Ws, const float* __restrict__ bs,
    short* __restrict__ wpA, short* __restrict__ wpM, short* __restrict__ wpB,
    short* __restrict__ wpC,
    float* __restrict__ biasA, float* __restrict__ biasM, float* __restrict__ biasB,
    float* __restrict__ biasC, int* __restrict__ cnt)
{
    int b = blockIdx.x, tid = threadIdx.x;
    for (int i = b * 256 + tid; i < 3 * NC; i += gridDim.x * 256) cnt[i] = 0;

    if (b < 48) {                             // atom composite pack: 96x128, S=3
        int idx = b * 256 + tid;
        int k = idx >> 7, col = idx & 127, c = col & 63;
        const float* WB = ((col < 64) ? Wf : Ws) + (size_t)6 * 2 * H * H + (size_t)H * H;
        float v = 0.0f;
        if (k < 92) {
            const float* a = Wa + (size_t)k * H;
            for (int j = 0; j < H; ++j) v = fmaf(a[j], WB[j * H + c], v);
        }
        wpA[pack_pos(k, col, 3)] = bf16_of(v);
    } else if (b < 80) {                      // motif composite pack: 64x128, S=2
        int idx = (b - 48) * 256 + tid;
        int k = idx >> 7, col = idx & 127, c = col & 63;
        const float* WB = ((col < 64) ? Wf : Ws) + (size_t)8 * 2 * H * H + (size_t)H * H;
        float v = 0.0f;
        if (k < 35) {
            const float* a = Wm + (size_t)k * H;
            for (int j = 0; j < H; ++j) v = fmaf(a[j], WB[j * H + c], v);
        }
        wpM[pack_pos(k, col, 2)] = bf16_of(v);
    } else if (b < 176) {                     // cell top-half relayout: 3 x 64x128, S=2
        int cu = b - 80;
        int rel = cu >> 5;
        int idx = (cu & 31) * 256 + tid;
        int k = idx >> 7, col = idx & 127, c = col & 63;
        float v = ((col < 64) ? Wf : Ws)[(size_t)(6 + rel) * 2 * H * H + (size_t)k * H + c];
        wpC[(size_t)rel * 8192 + pack_pos(k, col, 2)] = bf16_of(v);
    } else if (b < 192) {                     // bond composite pack: 32x128, S=1
        int idx = (b - 176) * 256 + tid;      // < 4096
        int k = idx >> 7, col = idx & 127, c = col & 63;
        const float* WB = ((col < 64) ? Wf : Ws) + (size_t)7 * 2 * H * H + (size_t)H * H;
        float v = 0.0f;
        if (k < 7) {
            const float* a = Wb + (size_t)k * H;
            for (int j = 0; j < H; ++j) v = fmaf(a[j], WB[j * H + c], v);
        }
        wpB[pack_pos(k, col, 1)] = bf16_of(v);
    } else if (b == 192) {
        if (tid < 128) {
            int col = tid, c = col & 63;
            const float* WB = ((col < 64) ? Wf : Ws) + (size_t)6 * 2 * H * H + (size_t)H * H;
            float v = 0.0f;
            for (int j = 0; j < H; ++j) v = fmaf(ba[j], WB[j * H + c], v);
            biasA[col] = v;
        }
    } else if (b == 193) {
        if (tid < 128) {
            int col = tid, c = col & 63;
            const float* WB = ((col < 64) ? Wf : Ws) + (size_t)8 * 2 * H * H + (size_t)H * H;
            float v = 0.0f;
            for (int j = 0; j < H; ++j) v = fmaf(bm[j], WB[j * H + c], v);
            biasM[col] = v;
        }
    } else if (b == 194) {
        if (tid < 128) {
            int col = tid, c = col & 63;
            const float* WB = ((col < 64) ? Wf : Ws) + (size_t)7 * 2 * H * H + (size_t)H * H;
            float v = 0.0f;
            for (int j = 0; j < H; ++j) v = fmaf(bb_[j], WB[j * H + c], v);
            biasB[col] = v;
        }
    } else {
        for (int i = tid; i < 384; i += 256) {
            int rel = i >> 7, col = i & 127, c = col & 63;
            biasC[rel * 128 + col] = ((col < 64) ? bf : bs)[(6 + rel) * H + c];
        }
    }
}

// ---------------- G build tile: one wave = 16 rows x 128 cols, coalesced stores -------
template<int K, int S, bool VEC>
__device__ __forceinline__ void gmfma_body(
    int blk, const float* __restrict__ x, const short* __restrict__ wp,
    const float* __restrict__ bias, __half2* __restrict__ g)
{
    int l = threadIdx.x & 63;
    int wv = threadIdx.x >> 6;
    int r0 = (blk * 4 + wv) * 16;
    int lrow = l & 15, q = l >> 4;

    float bF[4], bS[4];
    #pragma unroll
    for (int t = 0; t < 4; ++t) {
        bF[t] = bias[lrow * 4 + t];           // col c = lrow*4 + t
        bS[t] = bias[64 + lrow * 4 + t];
    }

    f32x4 acc[8];
    #pragma unroll
    for (int t = 0; t < 8; ++t) acc[t] = (f32x4){0.f, 0.f, 0.f, 0.f};

    const float* xr = x + (size_t)(r0 + lrow) * K;
    #pragma unroll
    for (int s = 0; s < S; ++s) {
        int kb = s * 32 + q * 8;
        bf16x8 afrag;
        if (VEC && kb + 8 <= K) {
            float4 v0 = *(const float4*)(xr + kb);
            float4 v1 = *(const float4*)(xr + kb + 4);
            afrag[0] = bf16_of(v0.x); afrag[1] = bf16_of(v0.y);
            afrag[2] = bf16_of(v0.z); afrag[3] = bf16_of(v0.w);
            afrag[4] = bf16_of(v1.x); afrag[5] = bf16_of(v1.y);
            afrag[6] = bf16_of(v1.z); afrag[7] = bf16_of(v1.w);
        } else {
            #pragma unroll
            for (int e = 0; e < 8; ++e) {
                float xv = 0.0f;
                if (kb + e < K) xv = xr[kb + e];
                afrag[e] = bf16_of(xv);
            }
        }
        #pragma unroll
        for (int t = 0; t < 8; ++t) {
            bf16x8 bt = *(const bf16x8*)(wp + (size_t)((t * S + s) * 64 + l) * 8);
            acc[t] = __builtin_amdgcn_mfma_f32_16x16x32_bf16(afrag, bt, acc[t], 0, 0, 0);
        }
    }

    #pragma unroll
    for (int r = 0; r < 4; ++r) {             // one dwordx4 per row
        __half2 h[4];
        #pragma unroll
        for (int t = 0; t < 4; ++t)
            h[t] = __floats2half2_rn(acc[t][r] + bF[t], acc[t + 4][r] + bS[t]);
        *(float4*)(g + (size_t)(r0 + q * 4 + r) * H + lrow * 4) = *(float4*)h;
    }
}

// ================= K1: work (3528 blocks, append FIRST, no LDS) =================
// [0,104): append  [104,200): cell C  [200,1224): atom G  [1224,3272): bond G
// [3272,3528): motif G.  gAll rows: [0,NA) atom | [NA,NA+NB) bond | [NA+NB,..) motif
__global__ __launch_bounds__(256) void work_kernel(
    const float* __restrict__ xa, const float* __restrict__ xb, const float* __restrict__ xm,
    const float* __restrict__ xc,
    const short* __restrict__ wpA, const float* __restrict__ biasA,
    const short* __restrict__ wpM, const float* __restrict__ biasM,
    const short* __restrict__ wpB, const float* __restrict__ biasB,
    const short* __restrict__ wpC, const float* __restrict__ biasC,
    const int* __restrict__ ea, const int* __restrict__ eb, const int* __restrict__ em,
    int* __restrict__ cnt, int* __restrict__ slots,
    __half2* __restrict__ gAll, __half2* __restrict__ Ccomb)
{
    int b = blockIdx.x, tid = threadIdx.x;
    if (b < 104) {                               // edge append (absolute gAll rows baked in)
        int t0 = b * 256 + tid;
        #pragma unroll
        for (int u2 = 0; u2 < 8; ++u2) {
            int i = t0 + u2 * 26624;
            int r, d, s;
            if (i < E_AC)             { r = 0; s = ea[i];                      d = ea[E_AC + i]; }
            else if (i < E_AC + E_BC) { int k = i - E_AC; r = 1; s = NA + eb[k]; d = eb[E_BC + k]; }
            else                      { int k = i - E_AC - E_BC; r = 2; s = NA + NB + em[k]; d = em[E_MC + k]; }
            int pos = atomicAdd(&cnt[r * NC + d], 1);
            int base, cap;
            if (r == 0)      { base = d * CAPA;         cap = CAPA; }
            else if (r == 1) { base = SLOTB + d * CAPB; cap = CAPB; }
            else             { base = SLOTM + d * CAPM; cap = CAPM; }
            if (pos < cap) slots[base + pos] = s;
        }
    } else if (b < 200) {                        // cell C build via MFMA relayout
        int cu = b - 104;
        int rel = cu >> 5, blk = cu & 31;
        gmfma_body<64, 2, true>(blk, xc, wpC + (size_t)rel * 8192, biasC + rel * 128,
                                Ccomb + (size_t)rel * NC * H);
    } else if (b < 1224) {
        gmfma_body<92, 3, true>(b - 200, xa, wpA, biasA, gAll);
    } else if (b < 3272) {
        gmfma_body<7, 1, false>(b - 1224, xb, wpB, biasB, gAll + (size_t)NA * H);
    } else {
        gmfma_body<35, 2, false>(b - 3272, xm, wpM, biasM, gAll + (size_t)(NA + NB) * H);
    }
}

// ================= K2: per-cell accumulate + head (2048 blocks x 512) =================
// Flattened edge loop, 2-deep software pipeline: load batch n+1 before computing batch n.
__global__ __launch_bounds__(512) void cellacc_kernel(
    const __half2* __restrict__ gAll,
    const int* __restrict__ slots, const int* __restrict__ cnt,
    const __half2* __restrict__ Ccomb, const float* __restrict__ xc,
    const float* __restrict__ Wp, const float* __restrict__ bp,
    const float* __restrict__ Wo, const float* __restrict__ bo,
    float* __restrict__ out)
{
    __shared__ int   sL[CAPA + CAPB + CAPM];   // 480 ints
    __shared__ float red[8][H];
    __shared__ float vL[H];
    int d = blockIdx.x;
    int tid = threadIdx.x, lane = tid & 63, wv = tid >> 6;   // 8 waves

    int nA = min(cnt[d], CAPA);
    int nB = min(cnt[NC + d], CAPB);
    int nM = min(cnt[2 * NC + d], CAPM);
    for (int i = tid; i < nA; i += 512) sL[i] = slots[d * CAPA + i];
    for (int i = tid; i < nB; i += 512) sL[nA + i] = slots[SLOTB + d * CAPB + i];
    for (int i = tid; i < nM; i += 512) sL[nA + nB + i] = slots[SLOTM + d * CAPM + i];
    float2 ccA = __half22float2(Ccomb[(size_t)d * H + lane]);
    float2 ccB = __half22float2(Ccomb[(size_t)(NC + d) * H + lane]);
    float2 ccM = __half22float2(Ccomb[(size_t)(2 * NC + d) * H + lane]);
    __syncthreads();

    int ntot = nA + nB + nM, nAB = nA + nB;
    float acc = 0.0f;
    int cs = (ntot + 7) >> 3;                  // contiguous chunk per wave
    int p0 = wv * cs, p1 = min(p0 + cs, ntot);

    // ---- two named register batches (static indexing only) ----
    float cx0[4], cy0[4], mk0[4]; float2 av0[4];
    float cx1[4], cy1[4], mk1[4]; float2 av1[4];

#define LOADB(P, CX, CY, MK, AV)                                              \
    {                                                                         \
        _Pragma("unroll")                                                     \
        for (int v = 0; v < 4; ++v) {                                         \
            int pc = (P) + v;                                                 \
            MK[v] = (pc < p1) ? 1.0f : 0.0f;                                  \
            pc = min(pc, ntot - 1);                                           \
            int row = sL[pc];                                                 \
            CX[v] = (pc < nA) ? ccA.x : (pc < nAB) ? ccB.x : ccM.x;           \
            CY[v] = (pc < nA) ? ccA.y : (pc < nAB) ? ccB.y : ccM.y;           \
            AV[v] = __half22float2(gAll[(size_t)row * H + lane]);             \
        }                                                                     \
    }
#define COMPB(CX, CY, MK, AV)                                                 \
    {                                                                         \
        _Pragma("unroll")                                                     \
        for (int v = 0; v < 4; ++v)                                           \
            acc += MK[v] * (sigmoidf_(CX[v] + AV[v].x)                        \
                            * softplusf_(CY[v] + AV[v].y));                   \
    }

    if (p0 < p1) {
        LOADB(p0, cx0, cy0, mk0, av0);
        for (int p = p0; p < p1; p += 8) {
            if (p + 4 < p1) LOADB(p + 4, cx1, cy1, mk1, av1);
            COMPB(cx0, cy0, mk0, av0);
            if (p + 8 < p1) LOADB(p + 8, cx0, cy0, mk0, av0);
            if (p + 4 < p1) COMPB(cx1, cy1, mk1, av1);
        }
    }
#undef LOADB
#undef COMPB

    red[wv][lane] = acc;
    __syncthreads();
    if (wv == 0) {
        float a = 3.0f * xc[(size_t)d * H + lane];
        #pragma unroll
        for (int w = 0; w < 8; ++w) a += red[w][lane];
        vL[lane] = fmaxf(a, 0.0f);
        __builtin_amdgcn_s_waitcnt(0);   // wave-local LDS drain
        float aj = bp[lane];
        #pragma unroll
        for (int k = 0; k < H; ++k) aj = fmaf(vL[k], Wp[k * H + lane], aj);
        float contrib = softplusf_(aj) * Wo[lane];
        #pragma unroll
        for (int o = 32; o > 0; o >>= 1) contrib += __shfl_down(contrib, o, 64);
        if (lane == 0) out[d] = contrib + bo[0];
    }
}

extern "C" void kernel_launch(void* const* d_in, const int* in_sizes, int n_in,
                              void* d_out, int out_size, void* d_ws, size_t ws_size,
                              hipStream_t stream)
{
    const float* xa = (const float*)d_in[0];
    const float* xb = (const float*)d_in[1];
    const float* xm = (const float*)d_in[2];
    const float* xc = (const float*)d_in[3];
    const float* Wa = (const float*)d_in[4];
    const float* ba = (const float*)d_in[5];
    const float* Wb = (const float*)d_in[6];
    const float* bb_ = (const float*)d_in[7];
    const float* Wm = (const float*)d_in[8];
    const float* bm = (const float*)d_in[9];
    const float* Wf = (const float*)d_in[10];
    const float* bf = (const float*)d_in[11];
    const float* Ws = (const float*)d_in[12];
    const float* bs = (const float*)d_in[13];
    const float* Wp = (const float*)d_in[14];
    const float* bp = (const float*)d_in[15];
    const float* Wo = (const float*)d_in[16];
    const float* bo = (const float*)d_in[17];
    const int* ea = (const int*)d_in[24];
    const int* eb = (const int*)d_in[25];
    const int* em = (const int*)d_in[26];

    // ---- workspace layout (256B-aligned), ~62 MB ----
    char* base = (char*)d_ws;
    size_t o = 0;
    auto alloc = [&](size_t bytes) { char* r = base + o; o = (o + bytes + 255) & ~(size_t)255; return r; };
    int*     cnt   = (int*)    alloc(3 * NC * sizeof(int));
    int*     slots = (int*)    alloc(SLOT_TOT * sizeof(int));
    short*   wpA   = (short*)  alloc(8 * 3 * 64 * 8 * sizeof(short));
    short*   wpM   = (short*)  alloc(8 * 2 * 64 * 8 * sizeof(short));
    short*   wpB   = (short*)  alloc(8 * 1 * 64 * 8 * sizeof(short));
    short*   wpC   = (short*)  alloc(3 * 8192 * sizeof(short));
    float*   biasA = (float*)  alloc(128 * sizeof(float));
    float*   biasM = (float*)  alloc(128 * sizeof(float));
    float*   biasB = (float*)  alloc(128 * sizeof(float));
    float*   biasC = (float*)  alloc(384 * sizeof(float));
    __half2* Ccomb = (__half2*)alloc((size_t)3 * NC * H * sizeof(__half2));
    __half2* gAll  = (__half2*)alloc((size_t)(NA + NB + NM) * H * sizeof(__half2));  // 54.5 MB
    float*   out   = (float*)d_out;

    prep0_kernel<<<196, 256, 0, stream>>>(Wa, ba, Wb, bb_, Wm, bm, Wf, bf, Ws, bs,
                                          wpA, wpM, wpB, wpC,
                                          biasA, biasM, biasB, biasC, cnt);
    work_kernel<<<3528, 256, 0, stream>>>(xa, xb, xm, xc,
                                          wpA, biasA, wpM, biasM, wpB, biasB, wpC, biasC,
                                          ea, eb, em, cnt, slots, gAll, Ccomb);
    cellacc_kernel<<<NC, 512, 0, stream>>>(gAll, slots, cnt, Ccomb,
                                           xc, Wp, bp, Wo, bo, out);
}

// Round 18
// 65.030 us; speedup vs baseline: 1.2282x; 1.0978x over previous
//
#include <hip/hip_runtime.h>
#include <hip/hip_fp16.h>

#define H 64
#define NA 65536
#define NB 131072
#define NM 16384
#define NC 2048
#define E_AC 65536
#define E_BC 131072
#define E_MC 16384
#define NE_TOT (E_AC + E_BC + E_MC)

#define CAPA 160
#define CAPB 224
#define CAPM 96
#define SLOTB (NC * CAPA)
#define SLOTM (SLOTB + NC * CAPB)
#define SLOT_TOT (SLOTM + NC * CAPM)

typedef __attribute__((ext_vector_type(8))) short bf16x8;
typedef __attribute__((ext_vector_type(4))) float f32x4;

__device__ __forceinline__ float sigmoidf_(float x) { return 1.0f / (1.0f + __expf(-x)); }
__device__ __forceinline__ float softplusf_(float x) {
    return fmaxf(x, 0.0f) + __logf(1.0f + __expf(-fabsf(x)));
}
__device__ __forceinline__ short bf16_of(float f) {
    union { float f; unsigned u; } v; v.f = f;
    unsigned r = (v.u + 0x7fff + ((v.u >> 16) & 1)) >> 16;  // RNE
    return (short)r;
}

// Column-permuted pack position: actual col c (0..63), part = 0(f)/1(s).
__device__ __forceinline__ size_t pack_pos(int k, int col, int S) {
    int part = col >> 6, c = col & 63;
    int t = (c & 3) + part * 4;
    int lo = c >> 2;
    int sm = k >> 5, q = (k >> 3) & 3, e = k & 7;
    return (size_t)(((t * S + sm) * 64) + q * 16 + lo) * 8 + e;
}

// ================= K0: prep0 — zero cnt + weight packs (196 blocks) =================
__global__ __launch_bounds__(256) void prep0_kernel(
    const float* __restrict__ Wa, const float* __restrict__ ba,
    const float* __restrict__ Wb, const float* __restrict__ bb_,
    const float* __restrict__ Wm, const float* __restrict__ bm,
    const float* __restrict__ Wf, const float* __restrict__ bf,
    const float* __restrict__ Ws, const float* __restrict__ bs,
    short* __restrict__ wpA, short* __restrict__ wpM, short* __restrict__ wpB,
    short* __restrict__ wpC,
    float* __restrict__ biasA, float* __restrict__ biasM, float* __restrict__ biasB,
    float* __restrict__ biasC, int* __restrict__ cnt)
{
    int b = blockIdx.x, tid = threadIdx.x;
    for (int i = b * 256 + tid; i < 3 * NC; i += gridDim.x * 256) cnt[i] = 0;

    if (b < 48) {                             // atom composite pack: 96x128, S=3
        int idx = b * 256 + tid;
        int k = idx >> 7, col = idx & 127, c = col & 63;
        const float* WB = ((col < 64) ? Wf : Ws) + (size_t)6 * 2 * H * H + (size_t)H * H;
        float v = 0.0f;
        if (k < 92) {
            const float* a = Wa + (size_t)k * H;
            for (int j = 0; j < H; ++j) v = fmaf(a[j], WB[j * H + c], v);
        }
        wpA[pack_pos(k, col, 3)] = bf16_of(v);
    } else if (b < 80) {                      // motif composite pack: 64x128, S=2
        int idx = (b - 48) * 256 + tid;
        int k = idx >> 7, col = idx & 127, c = col & 63;
        const float* WB = ((col < 64) ? Wf : Ws) + (size_t)8 * 2 * H * H + (size_t)H * H;
        float v = 0.0f;
        if (k < 35) {
            const float* a = Wm + (size_t)k * H;
            for (int j = 0; j < H; ++j) v = fmaf(a[j], WB[j * H + c], v);
        }
        wpM[pack_pos(k, col, 2)] = bf16_of(v);
    } else if (b < 176) {                     // cell top-half relayout: 3 x 64x128, S=2
        int cu = b - 80;
        int rel = cu >> 5;
        int idx = (cu & 31) * 256 + tid;
        int k = idx >> 7, col = idx & 127, c = col & 63;
        float v = ((col < 64) ? Wf : Ws)[(size_t)(6 + rel) * 2 * H * H + (size_t)k * H + c];
        wpC[(size_t)rel * 8192 + pack_pos(k, col, 2)] = bf16_of(v);
    } else if (b < 192) {                     // bond composite pack: 32x128, S=1
        int idx = (b - 176) * 256 + tid;
        int k = idx >> 7, col = idx & 127, c = col & 63;
        const float* WB = ((col < 64) ? Wf : Ws) + (size_t)7 * 2 * H * H + (size_t)H * H;
        float v = 0.0f;
        if (k < 7) {
            const float* a = Wb + (size_t)k * H;
            for (int j = 0; j < H; ++j) v = fmaf(a[j], WB[j * H + c], v);
        }
        wpB[pack_pos(k, col, 1)] = bf16_of(v);
    } else if (b == 192) {
        if (tid < 128) {
            int col = tid, c = col & 63;
            const float* WB = ((col < 64) ? Wf : Ws) + (size_t)6 * 2 * H * H + (size_t)H * H;
            float v = 0.0f;
            for (int j = 0; j < H; ++j) v = fmaf(ba[j], WB[j * H + c], v);
            biasA[col] = v;
        }
    } else if (b == 193) {
        if (tid < 128) {
            int col = tid, c = col & 63;
            const float* WB = ((col < 64) ? Wf : Ws) + (size_t)8 * 2 * H * H + (size_t)H * H;
            float v = 0.0f;
            for (int j = 0; j < H; ++j) v = fmaf(bm[j], WB[j * H + c], v);
            biasM[col] = v;
        }
    } else if (b == 194) {
        if (tid < 128) {
            int col = tid, c = col & 63;
            const float* WB = ((col < 64) ? Wf : Ws) + (size_t)7 * 2 * H * H + (size_t)H * H;
            float v = 0.0f;
            for (int j = 0; j < H; ++j) v = fmaf(bb_[j], WB[j * H + c], v);
            biasB[col] = v;
        }
    } else {
        for (int i = tid; i < 384; i += 256) {
            int rel = i >> 7, col = i & 127, c = col & 63;
            biasC[rel * 128 + col] = ((col < 64) ? bf : bs)[(6 + rel) * H + c];
        }
    }
}

// ---------------- G build tile: one wave = 16 rows x 128 cols, coalesced stores -------
template<int K, int S, bool VEC>
__device__ __forceinline__ void gmfma_body(
    int blk, const float* __restrict__ x, const short* __restrict__ wp,
    const float* __restrict__ bias, __half2* __restrict__ g)
{
    int l = threadIdx.x & 63;
    int wv = threadIdx.x >> 6;
    int r0 = (blk * 4 + wv) * 16;
    int lrow = l & 15, q = l >> 4;

    float bF[4], bS[4];
    #pragma unroll
    for (int t = 0; t < 4; ++t) {
        bF[t] = bias[lrow * 4 + t];
        bS[t] = bias[64 + lrow * 4 + t];
    }

    f32x4 acc[8];
    #pragma unroll
    for (int t = 0; t < 8; ++t) acc[t] = (f32x4){0.f, 0.f, 0.f, 0.f};

    const float* xr = x + (size_t)(r0 + lrow) * K;
    #pragma unroll
    for (int s = 0; s < S; ++s) {
        int kb = s * 32 + q * 8;
        bf16x8 afrag;
        if (VEC && kb + 8 <= K) {
            float4 v0 = *(const float4*)(xr + kb);
            float4 v1 = *(const float4*)(xr + kb + 4);
            afrag[0] = bf16_of(v0.x); afrag[1] = bf16_of(v0.y);
            afrag[2] = bf16_of(v0.z); afrag[3] = bf16_of(v0.w);
            afrag[4] = bf16_of(v1.x); afrag[5] = bf16_of(v1.y);
            afrag[6] = bf16_of(v1.z); afrag[7] = bf16_of(v1.w);
        } else {
            #pragma unroll
            for (int e = 0; e < 8; ++e) {
                float xv = 0.0f;
                if (kb + e < K) xv = xr[kb + e];
                afrag[e] = bf16_of(xv);
            }
        }
        #pragma unroll
        for (int t = 0; t < 8; ++t) {
            bf16x8 bt = *(const bf16x8*)(wp + (size_t)((t * S + s) * 64 + l) * 8);
            acc[t] = __builtin_amdgcn_mfma_f32_16x16x32_bf16(afrag, bt, acc[t], 0, 0, 0);
        }
    }

    #pragma unroll
    for (int r = 0; r < 4; ++r) {
        __half2 h[4];
        #pragma unroll
        for (int t = 0; t < 4; ++t)
            h[t] = __floats2half2_rn(acc[t][r] + bF[t], acc[t + 4][r] + bS[t]);
        *(float4*)(g + (size_t)(r0 + q * 4 + r) * H + lrow * 4) = *(float4*)h;
    }
}

// ================= K1: work (3528 blocks, append FIRST, no LDS) =================
__global__ __launch_bounds__(256) void work_kernel(
    const float* __restrict__ xa, const float* __restrict__ xb, const float* __restrict__ xm,
    const float* __restrict__ xc,
    const short* __restrict__ wpA, const float* __restrict__ biasA,
    const short* __restrict__ wpM, const float* __restrict__ biasM,
    const short* __restrict__ wpB, const float* __restrict__ biasB,
    const short* __restrict__ wpC, const float* __restrict__ biasC,
    const int* __restrict__ ea, const int* __restrict__ eb, const int* __restrict__ em,
    int* __restrict__ cnt, int* __restrict__ slots,
    __half2* __restrict__ gAll, __half2* __restrict__ Ccomb)
{
    int b = blockIdx.x, tid = threadIdx.x;
    if (b < 104) {                               // edge append (absolute gAll rows baked in)
        int t0 = b * 256 + tid;
        #pragma unroll
        for (int u2 = 0; u2 < 8; ++u2) {
            int i = t0 + u2 * 26624;
            int r, d, s;
            if (i < E_AC)             { r = 0; s = ea[i];                      d = ea[E_AC + i]; }
            else if (i < E_AC + E_BC) { int k = i - E_AC; r = 1; s = NA + eb[k]; d = eb[E_BC + k]; }
            else                      { int k = i - E_AC - E_BC; r = 2; s = NA + NB + em[k]; d = em[E_MC + k]; }
            int pos = atomicAdd(&cnt[r * NC + d], 1);
            int base, cap;
            if (r == 0)      { base = d * CAPA;         cap = CAPA; }
            else if (r == 1) { base = SLOTB + d * CAPB; cap = CAPB; }
            else             { base = SLOTM + d * CAPM; cap = CAPM; }
            if (pos < cap) slots[base + pos] = s;
        }
    } else if (b < 200) {
        int cu = b - 104;
        int rel = cu >> 5, blk = cu & 31;
        gmfma_body<64, 2, true>(blk, xc, wpC + (size_t)rel * 8192, biasC + rel * 128,
                                Ccomb + (size_t)rel * NC * H);
    } else if (b < 1224) {
        gmfma_body<92, 3, true>(b - 200, xa, wpA, biasA, gAll);
    } else if (b < 3272) {
        gmfma_body<7, 1, false>(b - 1224, xb, wpB, biasB, gAll + (size_t)NA * H);
    } else {
        gmfma_body<35, 2, false>(b - 3272, xm, wpM, biasM, gAll + (size_t)(NA + NB) * H);
    }
}

// ================= K2: per-cell accumulate + head (2048 blocks x 256, 4 waves) =========
// Finer blocks (8/CU resident), flattened gather loop, head parallelized across 4 waves.
__global__ __launch_bounds__(256) void cellacc_kernel(
    const __half2* __restrict__ gAll,
    const int* __restrict__ slots, const int* __restrict__ cnt,
    const __half2* __restrict__ Ccomb, const float* __restrict__ xc,
    const float* __restrict__ Wp, const float* __restrict__ bp,
    const float* __restrict__ Wo, const float* __restrict__ bo,
    float* __restrict__ out)
{
    __shared__ int   sL[CAPA + CAPB + CAPM];   // 480 ints
    __shared__ float red[4][H];
    __shared__ float vL[H];
    int d = blockIdx.x;
    int tid = threadIdx.x, lane = tid & 63, wv = tid >> 6;   // 4 waves

    int nA = min(cnt[d], CAPA);
    int nB = min(cnt[NC + d], CAPB);
    int nM = min(cnt[2 * NC + d], CAPM);
    for (int i = tid; i < nA; i += 256) sL[i] = slots[d * CAPA + i];
    for (int i = tid; i < nB; i += 256) sL[nA + i] = slots[SLOTB + d * CAPB + i];
    for (int i = tid; i < nM; i += 256) sL[nA + nB + i] = slots[SLOTM + d * CAPM + i];
    float2 ccA = __half22float2(Ccomb[(size_t)d * H + lane]);
    float2 ccB = __half22float2(Ccomb[(size_t)(NC + d) * H + lane]);
    float2 ccM = __half22float2(Ccomb[(size_t)(2 * NC + d) * H + lane]);
    __syncthreads();

    int ntot = nA + nB + nM, nAB = nA + nB;
    float acc = 0.0f;
    int cs = (ntot + 3) >> 2;                  // contiguous chunk per wave
    int p0 = wv * cs, p1 = min(p0 + cs, ntot);

    for (int p = p0; p < p1; p += 4) {
        float cx[4], cy[4], mk[4]; float2 av[4];
        #pragma unroll
        for (int v = 0; v < 4; ++v) {
            int pc = p + v;
            mk[v] = (pc < p1) ? 1.0f : 0.0f;
            pc = min(pc, ntot - 1);
            int row = sL[pc];
            cx[v] = (pc < nA) ? ccA.x : (pc < nAB) ? ccB.x : ccM.x;
            cy[v] = (pc < nA) ? ccA.y : (pc < nAB) ? ccB.y : ccM.y;
            av[v] = __half22float2(gAll[(size_t)row * H + lane]);
        }
        #pragma unroll
        for (int v = 0; v < 4; ++v)
            acc += mk[v] * (sigmoidf_(cx[v] + av[v].x) * softplusf_(cy[v] + av[v].y));
    }

    red[wv][lane] = acc;
    __syncthreads();
    if (wv == 0) {
        float a = 3.0f * xc[(size_t)d * H + lane]
                + red[0][lane] + red[1][lane] + red[2][lane] + red[3][lane];
        vL[lane] = fmaxf(a, 0.0f);
    }
    __syncthreads();

    // head matvec split over 4 waves: wave wv covers k in [wv*16, wv*16+16)
    float aj = (wv == 0) ? bp[lane] : 0.0f;
    #pragma unroll
    for (int kk = 0; kk < 16; ++kk) {
        int k = wv * 16 + kk;
        aj = fmaf(vL[k], Wp[k * H + lane], aj);
    }
    red[wv][lane] = aj;
    __syncthreads();
    if (wv == 0) {
        float ajs = red[0][lane] + red[1][lane] + red[2][lane] + red[3][lane];
        float contrib = softplusf_(ajs) * Wo[lane];
        #pragma unroll
        for (int o = 32; o > 0; o >>= 1) contrib += __shfl_down(contrib, o, 64);
        if (lane == 0) out[d] = contrib + bo[0];
    }
}

extern "C" void kernel_launch(void* const* d_in, const int* in_sizes, int n_in,
                              void* d_out, int out_size, void* d_ws, size_t ws_size,
                              hipStream_t stream)
{
    const float* xa = (const float*)d_in[0];
    const float* xb = (const float*)d_in[1];
    const float* xm = (const float*)d_in[2];
    const float* xc = (const float*)d_in[3];
    const float* Wa = (const float*)d_in[4];
    const float* ba = (const float*)d_in[5];
    const float* Wb = (const float*)d_in[6];
    const float* bb_ = (const float*)d_in[7];
    const float* Wm = (const float*)d_in[8];
    const float* bm = (const float*)d_in[9];
    const float* Wf = (const float*)d_in[10];
    const float* bf = (const float*)d_in[11];
    const float* Ws = (const float*)d_in[12];
    const float* bs = (const float*)d_in[13];
    const float* Wp = (const float*)d_in[14];
    const float* bp = (const float*)d_in[15];
    const float* Wo = (const float*)d_in[16];
    const float* bo = (const float*)d_in[17];
    const int* ea = (const int*)d_in[24];
    const int* eb = (const int*)d_in[25];
    const int* em = (const int*)d_in[26];

    // ---- workspace layout (256B-aligned), ~62 MB ----
    char* base = (char*)d_ws;
    size_t o = 0;
    auto alloc = [&](size_t bytes) { char* r = base + o; o = (o + bytes + 255) & ~(size_t)255; return r; };
    int*     cnt   = (int*)    alloc(3 * NC * sizeof(int));
    int*     slots = (int*)    alloc(SLOT_TOT * sizeof(int));
    short*   wpA   = (short*)  alloc(8 * 3 * 64 * 8 * sizeof(short));
    short*   wpM   = (short*)  alloc(8 * 2 * 64 * 8 * sizeof(short));
    short*   wpB   = (short*)  alloc(8 * 1 * 64 * 8 * sizeof(short));
    short*   wpC   = (short*)  alloc(3 * 8192 * sizeof(short));
    float*   biasA = (float*)  alloc(128 * sizeof(float));
    float*   biasM = (float*)  alloc(128 * sizeof(float));
    float*   biasB = (float*)  alloc(128 * sizeof(float));
    float*   biasC = (float*)  alloc(384 * sizeof(float));
    __half2* Ccomb = (__half2*)alloc((size_t)3 * NC * H * sizeof(__half2));
    __half2* gAll  = (__half2*)alloc((size_t)(NA + NB + NM) * H * sizeof(__half2));  // 54.5 MB
    float*   out   = (float*)d_out;

    prep0_kernel<<<196, 256, 0, stream>>>(Wa, ba, Wb, bb_, Wm, bm, Wf, bf, Ws, bs,
                                          wpA, wpM, wpB, wpC,
                                          biasA, biasM, biasB, biasC, cnt);
    work_kernel<<<3528, 256, 0, stream>>>(xa, xb, xm, xc,
                                          wpA, biasA, wpM, biasM, wpB, biasB, wpC, biasC,
                                          ea, eb, em, cnt, slots, gAll, Ccomb);
    cellacc_kernel<<<NC, 256, 0, stream>>>(gAll, slots, cnt, Ccomb,
                                           xc, Wp, bp, Wo, bo, out);
}

// Round 19
// 64.682 us; speedup vs baseline: 1.2348x; 1.0054x over previous
//
#include <hip/hip_runtime.h>
#include <hip/hip_fp16.h>

#define H 64
#define NA 65536
#define NB 131072
#define NM 16384
#define NC 2048
#define E_AC 65536
#define E_BC 131072
#define E_MC 16384
#define NE_TOT (E_AC + E_BC + E_MC)

#define CAPA 160
#define CAPB 224
#define CAPM 96
#define SLOTB (NC * CAPA)
#define SLOTM (SLOTB + NC * CAPB)
#define SLOT_TOT (SLOTM + NC * CAPM)

typedef __attribute__((ext_vector_type(8))) short bf16x8;
typedef __attribute__((ext_vector_type(4))) float f32x4;

__device__ __forceinline__ float sigmoidf_(float x) { return 1.0f / (1.0f + __expf(-x)); }
__device__ __forceinline__ float softplusf_(float x) {
    return fmaxf(x, 0.0f) + __logf(1.0f + __expf(-fabsf(x)));
}
__device__ __forceinline__ short bf16_of(float f) {
    union { float f; unsigned u; } v; v.f = f;
    unsigned r = (v.u + 0x7fff + ((v.u >> 16) & 1)) >> 16;  // RNE
    return (short)r;
}

// Column-permuted pack position: actual col c (0..63), part = 0(f)/1(s).
__device__ __forceinline__ size_t pack_pos(int k, int col, int S) {
    int part = col >> 6, c = col & 63;
    int t = (c & 3) + part * 4;
    int lo = c >> 2;
    int sm = k >> 5, q = (k >> 3) & 3, e = k & 7;
    return (size_t)(((t * S + sm) * 64) + q * 16 + lo) * 8 + e;
}

// ================= K0: prep0 — zero cnt + weight packs (196 blocks) =================
__global__ __launch_bounds__(256) void prep0_kernel(
    const float* __restrict__ Wa, const float* __restrict__ ba,
    const float* __restrict__ Wb, const float* __restrict__ bb_,
    const float* __restrict__ Wm, const float* __restrict__ bm,
    const float* __restrict__ Wf, const float* __restrict__ bf,
    const float* __restrict__ Ws, const float* __restrict__ bs,
    short* __restrict__ wpA, short* __restrict__ wpM, short* __restrict__ wpB,
    short* __restrict__ wpC,
    float* __restrict__ biasA, float* __restrict__ biasM, float* __restrict__ biasB,
    float* __restrict__ biasC, int* __restrict__ cnt)
{
    int b = blockIdx.x, tid = threadIdx.x;
    for (int i = b * 256 + tid; i < 3 * NC; i += gridDim.x * 256) cnt[i] = 0;

    if (b < 48) {                             // atom composite pack: 96x128, S=3
        int idx = b * 256 + tid;
        int k = idx >> 7, col = idx & 127, c = col & 63;
        const float* WB = ((col < 64) ? Wf : Ws) + (size_t)6 * 2 * H * H + (size_t)H * H;
        float v = 0.0f;
        if (k < 92) {
            const float* a = Wa + (size_t)k * H;
            for (int j = 0; j < H; ++j) v = fmaf(a[j], WB[j * H + c], v);
        }
        wpA[pack_pos(k, col, 3)] = bf16_of(v);
    } else if (b < 80) {                      // motif composite pack: 64x128, S=2
        int idx = (b - 48) * 256 + tid;
        int k = idx >> 7, col = idx & 127, c = col & 63;
        const float* WB = ((col < 64) ? Wf : Ws) + (size_t)8 * 2 * H * H + (size_t)H * H;
        float v = 0.0f;
        if (k < 35) {
            const float* a = Wm + (size_t)k * H;
            for (int j = 0; j < H; ++j) v = fmaf(a[j], WB[j * H + c], v);
        }
        wpM[pack_pos(k, col, 2)] = bf16_of(v);
    } else if (b < 176) {                     // cell top-half relayout: 3 x 64x128, S=2
        int cu = b - 80;
        int rel = cu >> 5;
        int idx = (cu & 31) * 256 + tid;
        int k = idx >> 7, col = idx & 127, c = col & 63;
        float v = ((col < 64) ? Wf : Ws)[(size_t)(6 + rel) * 2 * H * H + (size_t)k * H + c];
        wpC[(size_t)rel * 8192 + pack_pos(k, col, 2)] = bf16_of(v);
    } else if (b < 192) {                     // bond composite pack: 32x128, S=1
        int idx = (b - 176) * 256 + tid;
        int k = idx >> 7, col = idx & 127, c = col & 63;
        const float* WB = ((col < 64) ? Wf : Ws) + (size_t)7 * 2 * H * H + (size_t)H * H;
        float v = 0.0f;
        if (k < 7) {
            const float* a = Wb + (size_t)k * H;
            for (int j = 0; j < H; ++j) v = fmaf(a[j], WB[j * H + c], v);
        }
        wpB[pack_pos(k, col, 1)] = bf16_of(v);
    } else if (b == 192) {
        if (tid < 128) {
            int col = tid, c = col & 63;
            const float* WB = ((col < 64) ? Wf : Ws) + (size_t)6 * 2 * H * H + (size_t)H * H;
            float v = 0.0f;
            for (int j = 0; j < H; ++j) v = fmaf(ba[j], WB[j * H + c], v);
            biasA[col] = v;
        }
    } else if (b == 193) {
        if (tid < 128) {
            int col = tid, c = col & 63;
            const float* WB = ((col < 64) ? Wf : Ws) + (size_t)8 * 2 * H * H + (size_t)H * H;
            float v = 0.0f;
            for (int j = 0; j < H; ++j) v = fmaf(bm[j], WB[j * H + c], v);
            biasM[col] = v;
        }
    } else if (b == 194) {
        if (tid < 128) {
            int col = tid, c = col & 63;
            const float* WB = ((col < 64) ? Wf : Ws) + (size_t)7 * 2 * H * H + (size_t)H * H;
            float v = 0.0f;
            for (int j = 0; j < H; ++j) v = fmaf(bb_[j], WB[j * H + c], v);
            biasB[col] = v;
        }
    } else {
        for (int i = tid; i < 384; i += 256) {
            int rel = i >> 7, col = i & 127, c = col & 63;
            biasC[rel * 128 + col] = ((col < 64) ? bf : bs)[(6 + rel) * H + c];
        }
    }
}

// ---------------- multi-tile G build: wave holds B-frags, does TILES x 16 rows --------
template<int K, int S, bool VEC, int TILES>
__device__ __forceinline__ void gmfma_multi(
    int blk, const float* __restrict__ x, const short* __restrict__ wp,
    const float* __restrict__ bias, __half2* __restrict__ g)
{
    int l = threadIdx.x & 63;
    int wv = threadIdx.x >> 6;
    int lrow = l & 15, q = l >> 4;
    int tile0 = (blk * 4 + wv) * TILES;

    bf16x8 bfrag[8][S];                       // loaded ONCE, reused TILES times
    #pragma unroll
    for (int t = 0; t < 8; ++t)
        #pragma unroll
        for (int s = 0; s < S; ++s)
            bfrag[t][s] = *(const bf16x8*)(wp + (size_t)((t * S + s) * 64 + l) * 8);

    float bF[4], bS[4];
    #pragma unroll
    for (int t = 0; t < 4; ++t) {
        bF[t] = bias[lrow * 4 + t];           // col c = lrow*4 + t
        bS[t] = bias[64 + lrow * 4 + t];
    }

    for (int tt = 0; tt < TILES; ++tt) {
        int r0 = (tile0 + tt) * 16;
        f32x4 acc[8];
        #pragma unroll
        for (int t = 0; t < 8; ++t) acc[t] = (f32x4){0.f, 0.f, 0.f, 0.f};

        const float* xr = x + (size_t)(r0 + lrow) * K;
        #pragma unroll
        for (int s = 0; s < S; ++s) {
            int kb = s * 32 + q * 8;
            bf16x8 afrag;
            if (VEC && kb + 8 <= K) {
                float4 v0 = *(const float4*)(xr + kb);
                float4 v1 = *(const float4*)(xr + kb + 4);
                afrag[0] = bf16_of(v0.x); afrag[1] = bf16_of(v0.y);
                afrag[2] = bf16_of(v0.z); afrag[3] = bf16_of(v0.w);
                afrag[4] = bf16_of(v1.x); afrag[5] = bf16_of(v1.y);
                afrag[6] = bf16_of(v1.z); afrag[7] = bf16_of(v1.w);
            } else {
                #pragma unroll
                for (int e = 0; e < 8; ++e) {
                    float xv = 0.0f;
                    if (kb + e < K) xv = xr[kb + e];
                    afrag[e] = bf16_of(xv);
                }
            }
            #pragma unroll
            for (int t = 0; t < 8; ++t)
                acc[t] = __builtin_amdgcn_mfma_f32_16x16x32_bf16(afrag, bfrag[t][s], acc[t], 0, 0, 0);
        }

        #pragma unroll
        for (int r = 0; r < 4; ++r) {         // one dwordx4 per row
            __half2 h[4];
            #pragma unroll
            for (int t = 0; t < 4; ++t)
                h[t] = __floats2half2_rn(acc[t][r] + bF[t], acc[t + 4][r] + bS[t]);
            *(float4*)(g + (size_t)(r0 + q * 4 + r) * H + lrow * 4) = *(float4*)h;
        }
    }
}

// ================= K1: work (960 blocks, TILES=4) =================
// [0,104): append  [104,616): bond G  [616,872): atom G  [872,936): motif G
// [936,960): cell C (8 blocks per rel)
__global__ __launch_bounds__(256) void work_kernel(
    const float* __restrict__ xa, const float* __restrict__ xb, const float* __restrict__ xm,
    const float* __restrict__ xc,
    const short* __restrict__ wpA, const float* __restrict__ biasA,
    const short* __restrict__ wpM, const float* __restrict__ biasM,
    const short* __restrict__ wpB, const float* __restrict__ biasB,
    const short* __restrict__ wpC, const float* __restrict__ biasC,
    const int* __restrict__ ea, const int* __restrict__ eb, const int* __restrict__ em,
    int* __restrict__ cnt, int* __restrict__ slots,
    __half2* __restrict__ gAll, __half2* __restrict__ Ccomb)
{
    int b = blockIdx.x, tid = threadIdx.x;
    if (b < 104) {                               // edge append (absolute gAll rows baked in)
        int t0 = b * 256 + tid;
        #pragma unroll
        for (int u2 = 0; u2 < 8; ++u2) {
            int i = t0 + u2 * 26624;
            int r, d, s;
            if (i < E_AC)             { r = 0; s = ea[i];                      d = ea[E_AC + i]; }
            else if (i < E_AC + E_BC) { int k = i - E_AC; r = 1; s = NA + eb[k]; d = eb[E_BC + k]; }
            else                      { int k = i - E_AC - E_BC; r = 2; s = NA + NB + em[k]; d = em[E_MC + k]; }
            int pos = atomicAdd(&cnt[r * NC + d], 1);
            int base, cap;
            if (r == 0)      { base = d * CAPA;         cap = CAPA; }
            else if (r == 1) { base = SLOTB + d * CAPB; cap = CAPB; }
            else             { base = SLOTM + d * CAPM; cap = CAPM; }
            if (pos < cap) slots[base + pos] = s;
        }
    } else if (b < 616) {
        gmfma_multi<7, 1, false, 4>(b - 104, xb, wpB, biasB, gAll + (size_t)NA * H);
    } else if (b < 872) {
        gmfma_multi<92, 3, true, 4>(b - 616, xa, wpA, biasA, gAll);
    } else if (b < 936) {
        gmfma_multi<35, 2, false, 4>(b - 872, xm, wpM, biasM, gAll + (size_t)(NA + NB) * H);
    } else {
        int cu = b - 936;
        int rel = cu >> 3, blk = cu & 7;
        gmfma_multi<64, 2, true, 4>(blk, xc, wpC + (size_t)rel * 8192, biasC + rel * 128,
                                    Ccomb + (size_t)rel * NC * H);
    }
}

// ================= K2: per-cell accumulate + head (2048 blocks x 256, 4 waves) =========
__global__ __launch_bounds__(256) void cellacc_kernel(
    const __half2* __restrict__ gAll,
    const int* __restrict__ slots, const int* __restrict__ cnt,
    const __half2* __restrict__ Ccomb, const float* __restrict__ xc,
    const float* __restrict__ Wp, const float* __restrict__ bp,
    const float* __restrict__ Wo, const float* __restrict__ bo,
    float* __restrict__ out)
{
    __shared__ int   sL[CAPA + CAPB + CAPM];   // 480 ints
    __shared__ float red[4][H];
    __shared__ float vL[H];
    int d = blockIdx.x;
    int tid = threadIdx.x, lane = tid & 63, wv = tid >> 6;   // 4 waves

    int nA = min(cnt[d], CAPA);
    int nB = min(cnt[NC + d], CAPB);
    int nM = min(cnt[2 * NC + d], CAPM);
    for (int i = tid; i < nA; i += 256) sL[i] = slots[d * CAPA + i];
    for (int i = tid; i < nB; i += 256) sL[nA + i] = slots[SLOTB + d * CAPB + i];
    for (int i = tid; i < nM; i += 256) sL[nA + nB + i] = slots[SLOTM + d * CAPM + i];
    float2 ccA = __half22float2(Ccomb[(size_t)d * H + lane]);
    float2 ccB = __half22float2(Ccomb[(size_t)(NC + d) * H + lane]);
    float2 ccM = __half22float2(Ccomb[(size_t)(2 * NC + d) * H + lane]);
    __syncthreads();

    int ntot = nA + nB + nM, nAB = nA + nB;
    float acc = 0.0f;
    int cs = (ntot + 3) >> 2;                  // contiguous chunk per wave
    int p0 = wv * cs, p1 = min(p0 + cs, ntot);

    for (int p = p0; p < p1; p += 4) {
        float cx[4], cy[4], mk[4]; float2 av[4];
        #pragma unroll
        for (int v = 0; v < 4; ++v) {
            int pc = p + v;
            mk[v] = (pc < p1) ? 1.0f : 0.0f;
            pc = min(pc, ntot - 1);
            int row = sL[pc];
            cx[v] = (pc < nA) ? ccA.x : (pc < nAB) ? ccB.x : ccM.x;
            cy[v] = (pc < nA) ? ccA.y : (pc < nAB) ? ccB.y : ccM.y;
            av[v] = __half22float2(gAll[(size_t)row * H + lane]);
        }
        #pragma unroll
        for (int v = 0; v < 4; ++v)
            acc += mk[v] * (sigmoidf_(cx[v] + av[v].x) * softplusf_(cy[v] + av[v].y));
    }

    red[wv][lane] = acc;
    __syncthreads();
    if (wv == 0) {
        float a = 3.0f * xc[(size_t)d * H + lane]
                + red[0][lane] + red[1][lane] + red[2][lane] + red[3][lane];
        vL[lane] = fmaxf(a, 0.0f);
    }
    __syncthreads();

    // head matvec split over 4 waves: wave wv covers k in [wv*16, wv*16+16)
    float aj = (wv == 0) ? bp[lane] : 0.0f;
    #pragma unroll
    for (int kk = 0; kk < 16; ++kk) {
        int k = wv * 16 + kk;
        aj = fmaf(vL[k], Wp[k * H + lane], aj);
    }
    red[wv][lane] = aj;
    __syncthreads();
    if (wv == 0) {
        float ajs = red[0][lane] + red[1][lane] + red[2][lane] + red[3][lane];
        float contrib = softplusf_(ajs) * Wo[lane];
        #pragma unroll
        for (int o = 32; o > 0; o >>= 1) contrib += __shfl_down(contrib, o, 64);
        if (lane == 0) out[d] = contrib + bo[0];
    }
}

extern "C" void kernel_launch(void* const* d_in, const int* in_sizes, int n_in,
                              void* d_out, int out_size, void* d_ws, size_t ws_size,
                              hipStream_t stream)
{
    const float* xa = (const float*)d_in[0];
    const float* xb = (const float*)d_in[1];
    const float* xm = (const float*)d_in[2];
    const float* xc = (const float*)d_in[3];
    const float* Wa = (const float*)d_in[4];
    const float* ba = (const float*)d_in[5];
    const float* Wb = (const float*)d_in[6];
    const float* bb_ = (const float*)d_in[7];
    const float* Wm = (const float*)d_in[8];
    const float* bm = (const float*)d_in[9];
    const float* Wf = (const float*)d_in[10];
    const float* bf = (const float*)d_in[11];
    const float* Ws = (const float*)d_in[12];
    const float* bs = (const float*)d_in[13];
    const float* Wp = (const float*)d_in[14];
    const float* bp = (const float*)d_in[15];
    const float* Wo = (const float*)d_in[16];
    const float* bo = (const float*)d_in[17];
    const int* ea = (const int*)d_in[24];
    const int* eb = (const int*)d_in[25];
    const int* em = (const int*)d_in[26];

    // ---- workspace layout (256B-aligned), ~62 MB ----
    char* base = (char*)d_ws;
    size_t o = 0;
    auto alloc = [&](size_t bytes) { char* r = base + o; o = (o + bytes + 255) & ~(size_t)255; return r; };
    int*     cnt   = (int*)    alloc(3 * NC * sizeof(int));
    int*     slots = (int*)    alloc(SLOT_TOT * sizeof(int));
    short*   wpA   = (short*)  alloc(8 * 3 * 64 * 8 * sizeof(short));
    short*   wpM   = (short*)  alloc(8 * 2 * 64 * 8 * sizeof(short));
    short*   wpB   = (short*)  alloc(8 * 1 * 64 * 8 * sizeof(short));
    short*   wpC   = (short*)  alloc(3 * 8192 * sizeof(short));
    float*   biasA = (float*)  alloc(128 * sizeof(float));
    float*   biasM = (float*)  alloc(128 * sizeof(float));
    float*   biasB = (float*)  alloc(128 * sizeof(float));
    float*   biasC = (float*)  alloc(384 * sizeof(float));
    __half2* Ccomb = (__half2*)alloc((size_t)3 * NC * H * sizeof(__half2));
    __half2* gAll  = (__half2*)alloc((size_t)(NA + NB + NM) * H * sizeof(__half2));  // 54.5 MB
    float*   out   = (float*)d_out;

    prep0_kernel<<<196, 256, 0, stream>>>(Wa, ba, Wb, bb_, Wm, bm, Wf, bf, Ws, bs,
                                          wpA, wpM, wpB, wpC,
                                          biasA, biasM, biasB, biasC, cnt);
    work_kernel<<<960, 256, 0, stream>>>(xa, xb, xm, xc,
                                         wpA, biasA, wpM, biasM, wpB, biasB, wpC, biasC,
                                         ea, eb, em, cnt, slots, gAll, Ccomb);
    cellacc_kernel<<<NC, 256, 0, stream>>>(gAll, slots, cnt, Ccomb,
                                           xc, Wp, bp, Wo, bo, out);
}